// Round 6
// baseline (271.863 us; speedup 1.0000x reference)
//
#include <hip/hip_runtime.h>

// SSIM (window=8 box sums) over 96 images of 512x512 fp32.
// v11 = v10 with TH 16 -> 8 (occupancy was grid-capped):
//  - v10 post-mortem: clean (VGPR 76, no spill, FETCH 224 MB ~= compulsory),
//    but grid 3072 waves = 12/CU = 37.5% occupancy cap; measured 27% occ,
//    27% VALUBusy, 1.9 TB/s. Latency-bound: ~140 VALU cyc/row then stall,
//    3 waves/SIMD can't cover load latency.
//  - TH=8: 6144 waves = 24/CU = 6/SIMD (VGPR 76 -> alloc 80 -> fits 6).
//    Overlap reads grow (15 rows per 8 output) but hit L2/L3 via swizzle.
//  - keep __launch_bounds__(64,2) (min_waves=4 proved to force 64-VGPR cap
//    and 200 MB spill in v7/v9); keep depth-1 prefetch (depth-2 costs 16
//    VGPR and would drop residency to 5/SIMD).
// Tripwires: WRITE_SIZE >> 96 KB => spill; VGPR must stay <= 80.

#define W 512
#define H 512
#define OW 505
#define OH 505
#define TH 8
#define NSTRIP ((OH + TH - 1) / TH)   // 64
#define NIMG 96
#define NWG (NSTRIP * NIMG)           // 6144, divisible by 8
#define NPIX (96.0 * 505.0 * 505.0)   // 24482400

__device__ __forceinline__ float4 ld4(const float* p) { return *(const float4*)p; }

__global__ void finalize(const double* p, float* out) {
    out[0] = 1.0f - (float)(*p / NPIX);
}

// unpack two float4s into a float[8]
#define UNPACK8(a0, a1, dst) {                                            \
        dst[0] = a0.x; dst[1] = a0.y; dst[2] = a0.z; dst[3] = a0.w;       \
        dst[4] = a1.x; dst[5] = a1.y; dst[6] = a1.z; dst[7] = a1.w;       \
    }

__global__ void __launch_bounds__(64, 2)
ssim_main(const float* __restrict__ gt, const float* __restrict__ ni,
          double* __restrict__ acc_out)
{
    const int l   = threadIdx.x;      // 0..63
    const int c0  = l * 8;            // own cols c0..c0+7

    // XCD-aware swizzle: HW assigns XCD = blockIdx % 8 (round-robin).
    // wid = xcd*768 + slot, strip-fastest: adjacent strips of one image run
    // on the SAME XCD -> 7-row strip-overlap re-reads hit that XCD's L2.
    const int b     = blockIdx.x;
    const int wid   = (b & 7) * (NWG / 8) + (b >> 3);
    const int strip = wid & (NSTRIP - 1);
    const int img   = wid >> 6;       // NSTRIP = 64

    const int R0  = strip * TH;       // first output row of strip
    const int R1  = min(R0 + TH, OH); // 1..8 output rows (strip 63 -> 1)

    const float C1 = 1e-4f;
    const float C2 = 9e-4f;

    const float* gx = gt + (size_t)img * (W * H) + c0;
    const float* gy = ni + (size_t)img * (W * H) + c0;

    // vertical 8-row window sums for own 8 columns
    float vsx[8], vsy[8], vsq[8], vsp[8];
#pragma unroll
    for (int j = 0; j < 8; ++j) { vsx[j] = 0.f; vsy[j] = 0.f; vsq[j] = 0.f; vsp[j] = 0.f; }

    // prefetch registers: incoming row (pi*), outgoing row (po*)
    float4 pix0, pix1, piy0, piy1;
    float4 pox0, pox1, poy0, poy1;

    // issue loads for row R0
    {
        const float* px = gx + (size_t)R0 * W;
        const float* py = gy + (size_t)R0 * W;
        pix0 = ld4(px); pix1 = ld4(px + 4);
        piy0 = ld4(py); piy1 = ld4(py + 4);
    }

    float acc = 0.0f;

    // ---- warmup: rows R0..R0+6, add-only; last iter prefetches row R0+7 ----
#pragma unroll 1
    for (int r = R0; r < R0 + 7; ++r) {
        float cx[8], cy[8];
        UNPACK8(pix0, pix1, cx)
        UNPACK8(piy0, piy1, cy)
        {   // issue next row's loads (row r+1 <= R0+7 <= 511, always valid)
            const float* px = gx + (size_t)(r + 1) * W;
            const float* py = gy + (size_t)(r + 1) * W;
            pix0 = ld4(px); pix1 = ld4(px + 4);
            piy0 = ld4(py); piy1 = ld4(py + 4);
        }
#pragma unroll
        for (int j = 0; j < 8; ++j) {
            vsx[j] = vsx[j] + cx[j];
            vsy[j] = vsy[j] + cy[j];
            vsq[j] = vsq[j] + (cx[j] * cx[j] + cy[j] * cy[j]);
            vsp[j] = vsp[j] + cx[j] * cy[j];
        }
    }

// horizontal sliding window + SSIM for output row; uses vs*, shuffles lane+1.
// lane 63's shuffle result is garbage but only feeds cols >= 505 (predicated).
#define HORIZ_SSIM() {                                                    \
        float nx[8], ny[8], nq[8], np_[8];                                \
        _Pragma("unroll")                                                 \
        for (int j = 0; j < 8; ++j) {                                     \
            nx[j]  = __shfl_down(vsx[j], 1);                              \
            ny[j]  = __shfl_down(vsy[j], 1);                              \
            nq[j]  = __shfl_down(vsq[j], 1);                              \
            np_[j] = __shfl_down(vsp[j], 1);                              \
        }                                                                 \
        float Sx = ((vsx[0] + vsx[1]) + (vsx[2] + vsx[3])) +              \
                   ((vsx[4] + vsx[5]) + (vsx[6] + vsx[7]));               \
        float Sy = ((vsy[0] + vsy[1]) + (vsy[2] + vsy[3])) +              \
                   ((vsy[4] + vsy[5]) + (vsy[6] + vsy[7]));               \
        float Sq = ((vsq[0] + vsq[1]) + (vsq[2] + vsq[3])) +              \
                   ((vsq[4] + vsq[5]) + (vsq[6] + vsq[7]));               \
        float Sp = ((vsp[0] + vsp[1]) + (vsp[2] + vsp[3])) +              \
                   ((vsp[4] + vsp[5]) + (vsp[6] + vsp[7]));               \
        _Pragma("unroll")                                                 \
        for (int j = 0; j < 8; ++j) {                                     \
            if (j) {                                                      \
                Sx += nx[j-1] - vsx[j-1];                                 \
                Sy += ny[j-1] - vsy[j-1];                                 \
                Sq += nq[j-1] - vsq[j-1];                                 \
                Sp += np_[j-1] - vsp[j-1];                                \
            }                                                             \
            float mu12 = Sx * Sy;                                         \
            float n1v = 2.0f * mu12 + C1;                                 \
            float n2v = 2.0f * (Sp - mu12) + C2;                          \
            float sx2 = Sx * Sx, sy2 = Sy * Sy;                           \
            float d1  = sx2 + sy2 + C1;                                   \
            float d2  = (Sq - sx2 - sy2) + C2;                            \
            float sv  = (n1v * n2v) * __builtin_amdgcn_rcpf(d1 * d2);     \
            if (c0 + j < OW) acc += sv;                                   \
        }                                                                 \
    }

    // ---- first output row o = R0 (window rows R0..R0+7), no outgoing ----
    {
        float cx[8], cy[8];
        UNPACK8(pix0, pix1, cx)
        UNPACK8(piy0, piy1, cy)
        // prefetch for o = R0+1: incoming row R0+8, outgoing row R0
        if (R0 + 1 < R1) {
            const float* px = gx + (size_t)(R0 + 8) * W;
            const float* py = gy + (size_t)(R0 + 8) * W;
            pix0 = ld4(px); pix1 = ld4(px + 4);
            piy0 = ld4(py); piy1 = ld4(py + 4);
            const float* qx = gx + (size_t)R0 * W;
            const float* qy = gy + (size_t)R0 * W;
            pox0 = ld4(qx); pox1 = ld4(qx + 4);
            poy0 = ld4(qy); poy1 = ld4(qy + 4);
        }
#pragma unroll
        for (int j = 0; j < 8; ++j) {
            vsx[j] = vsx[j] + cx[j];
            vsy[j] = vsy[j] + cy[j];
            vsq[j] = vsq[j] + (cx[j] * cx[j] + cy[j] * cy[j]);
            vsp[j] = vsp[j] + cx[j] * cy[j];
        }
        HORIZ_SSIM()
    }

    // ---- main loop: o = R0+1 .. R1-1 ----
    // window rows o..o+7: add incoming row o+7 (pi*), subtract outgoing row
    // o-1 (po*).  Prefetch for o+1: incoming o+8 (<= R1+6 <= 511), outgoing o.
#pragma unroll 1
    for (int o = R0 + 1; o < R1; ++o) {
        float cx[8], cy[8], ox[8], oy[8];
        UNPACK8(pix0, pix1, cx)
        UNPACK8(piy0, piy1, cy)
        UNPACK8(pox0, pox1, ox)
        UNPACK8(poy0, poy1, oy)
        if (o + 1 < R1) {
            const float* px = gx + (size_t)(o + 8) * W;
            const float* py = gy + (size_t)(o + 8) * W;
            pix0 = ld4(px); pix1 = ld4(px + 4);
            piy0 = ld4(py); piy1 = ld4(py + 4);
            const float* qx = gx + (size_t)o * W;
            const float* qy = gy + (size_t)o * W;
            pox0 = ld4(qx); pox1 = ld4(qx + 4);
            poy0 = ld4(qy); poy1 = ld4(qy + 4);
        }
#pragma unroll
        for (int j = 0; j < 8; ++j) {
            // same arithmetic order as v8: (vs - out) + in
            vsx[j] = (vsx[j] - ox[j]) + cx[j];
            vsy[j] = (vsy[j] - oy[j]) + cy[j];
            vsq[j] = vsq[j] + ((cx[j] * cx[j] + cy[j] * cy[j]) -
                               (ox[j] * ox[j] + oy[j] * oy[j]));
            vsp[j] = vsp[j] + (cx[j] * cy[j] - ox[j] * oy[j]);
        }
        HORIZ_SSIM()
    }

    // ---- reduction: single wave -> one double atomic ----
#pragma unroll
    for (int off = 32; off > 0; off >>= 1) acc += __shfl_down(acc, off);
    if (l == 0) atomicAdd(acc_out, (double)acc);
}

extern "C" void kernel_launch(void* const* d_in, const int* in_sizes, int n_in,
                              void* d_out, int out_size, void* d_ws, size_t ws_size,
                              hipStream_t stream) {
    const float* gt = (const float*)d_in[0];
    const float* ni = (const float*)d_in[1];
    double* acc = (double*)d_ws;   // 8 bytes scratch, re-poisoned every call

    hipMemsetAsync(acc, 0, sizeof(double), stream);
    ssim_main<<<dim3(NWG), 64, 0, stream>>>(gt, ni, acc);
    finalize<<<1, 1, 0, stream>>>(acc, (float*)d_out);
}

// Round 7
// 264.345 us; speedup vs baseline: 1.0284x; 1.0284x over previous
//
#include <hip/hip_runtime.h>

// SSIM (window=8 box sums) over 96 images of 512x512 fp32.
// v12 = v10 (TH=16, wave-per-strip, no LDS/barriers, XCD swizzle) + depth-2
// incoming-row prefetch:
//  - v11 post-mortem: doubling waves (12->24/CU) moved occupancy 27.3->28.6
//    and VALUBusy not at all -> NOT wave-starved.  Wave lifetime ~9000 cyc/row
//    vs ~380 issue cyc -> latency-serialized at depth-1 prefetch.
//  - v12: ping-pong slots A/B for incoming rows (consume row issued 2 iters
//    ago), manual 2x unroll with named float4 regs (no runtime indexing).
//    Outgoing rows stay depth-1 (L2-hit: same wave loaded them 8 rows ago).
//  - TH=16 (v10 beat v11 120 vs 128; TLP proven useless, less warmup).
// Tripwires: WRITE_SIZE >> 96 KB => spill; VGPR must stay <= 128.

#define W 512
#define H 512
#define OW 505
#define OH 505
#define TH 16
#define NSTRIP ((OH + TH - 1) / TH)   // 32
#define NIMG 96
#define NWG (NSTRIP * NIMG)           // 3072, divisible by 8
#define NPIX (96.0 * 505.0 * 505.0)   // 24482400

__device__ __forceinline__ float4 ld4(const float* p) { return *(const float4*)p; }

__global__ void finalize(const double* p, float* out) {
    out[0] = 1.0f - (float)(*p / NPIX);
}

// unpack two float4s into a float[8]
#define UNPACK8(a0, a1, dst) {                                            \
        dst[0] = a0.x; dst[1] = a0.y; dst[2] = a0.z; dst[3] = a0.w;       \
        dst[4] = a1.x; dst[5] = a1.y; dst[6] = a1.z; dst[7] = a1.w;       \
    }

__global__ void __launch_bounds__(64, 2)
ssim_main(const float* __restrict__ gt, const float* __restrict__ ni,
          double* __restrict__ acc_out)
{
    const int l   = threadIdx.x;      // 0..63
    const int c0  = l * 8;            // own cols c0..c0+7

    // XCD-aware swizzle: HW assigns XCD = blockIdx % 8 (round-robin).
    // wid = xcd*384 + slot, strip-fastest: adjacent strips of one image run
    // on the SAME XCD -> strip-overlap re-reads hit that XCD's L2.
    const int b     = blockIdx.x;
    const int wid   = (b & 7) * (NWG / 8) + (b >> 3);
    const int strip = wid & (NSTRIP - 1);
    const int img   = wid >> 5;       // NSTRIP = 32

    const int R0  = strip * TH;       // first output row of strip
    const int R1  = min(R0 + TH, OH); // >= 9 output rows per strip

    const float C1 = 1e-4f;
    const float C2 = 9e-4f;

    const float* gx = gt + (size_t)img * (W * H) + c0;
    const float* gy = ni + (size_t)img * (W * H) + c0;

    // vertical 8-row window sums for own 8 columns
    float vsx[8], vsy[8], vsq[8], vsp[8];
#pragma unroll
    for (int j = 0; j < 8; ++j) { vsx[j] = 0.f; vsy[j] = 0.f; vsq[j] = 0.f; vsp[j] = 0.f; }

    // incoming ping-pong slots A/B (one image row each: x in *x0,*x1; y in *y0,*y1)
    float4 ax0, ax1, ay0, ay1;
    float4 bx0, bx1, by0, by1;
    // outgoing slot (depth-1, L2-hit)
    float4 px0, px1, py0, py1;

    float acc = 0.0f;

#define ISSUE(X0, X1, Y0, Y1, row) {                                      \
        const float* p_ = gx + (size_t)(row) * W;                         \
        const float* q_ = gy + (size_t)(row) * W;                         \
        X0 = ld4(p_); X1 = ld4(p_ + 4);                                   \
        Y0 = ld4(q_); Y1 = ld4(q_ + 4);                                   \
    }

// warmup step: consume slot (row R0+roff), re-issue slot <- row R0+roff+2,
// accumulate add-only.  roff+2 <= 8 -> row <= R0+8 <= 504, always valid.
#define WARM(roff, X0, X1, Y0, Y1) {                                      \
        float cx[8], cy[8];                                               \
        UNPACK8(X0, X1, cx)                                               \
        UNPACK8(Y0, Y1, cy)                                               \
        ISSUE(X0, X1, Y0, Y1, R0 + (roff) + 2)                            \
        _Pragma("unroll")                                                 \
        for (int j = 0; j < 8; ++j) {                                     \
            vsx[j] = vsx[j] + cx[j];                                      \
            vsy[j] = vsy[j] + cy[j];                                      \
            vsq[j] = vsq[j] + (cx[j] * cx[j] + cy[j] * cy[j]);            \
            vsp[j] = vsp[j] + cx[j] * cy[j];                              \
        }                                                                 \
    }

// horizontal sliding window + SSIM for one output row; shuffles lane+1.
// lane 63's shuffle result is garbage but only feeds cols >= 505 (predicated).
#define HORIZ_SSIM() {                                                    \
        float nx[8], ny[8], nq[8], np_[8];                                \
        _Pragma("unroll")                                                 \
        for (int j = 0; j < 8; ++j) {                                     \
            nx[j]  = __shfl_down(vsx[j], 1);                              \
            ny[j]  = __shfl_down(vsy[j], 1);                              \
            nq[j]  = __shfl_down(vsq[j], 1);                              \
            np_[j] = __shfl_down(vsp[j], 1);                              \
        }                                                                 \
        float Sx = ((vsx[0] + vsx[1]) + (vsx[2] + vsx[3])) +              \
                   ((vsx[4] + vsx[5]) + (vsx[6] + vsx[7]));               \
        float Sy = ((vsy[0] + vsy[1]) + (vsy[2] + vsy[3])) +              \
                   ((vsy[4] + vsy[5]) + (vsy[6] + vsy[7]));               \
        float Sq = ((vsq[0] + vsq[1]) + (vsq[2] + vsq[3])) +              \
                   ((vsq[4] + vsq[5]) + (vsq[6] + vsq[7]));               \
        float Sp = ((vsp[0] + vsp[1]) + (vsp[2] + vsp[3])) +              \
                   ((vsp[4] + vsp[5]) + (vsp[6] + vsp[7]));               \
        _Pragma("unroll")                                                 \
        for (int j = 0; j < 8; ++j) {                                     \
            if (j) {                                                      \
                Sx += nx[j-1] - vsx[j-1];                                 \
                Sy += ny[j-1] - vsy[j-1];                                 \
                Sq += nq[j-1] - vsq[j-1];                                 \
                Sp += np_[j-1] - vsp[j-1];                                \
            }                                                             \
            float mu12 = Sx * Sy;                                         \
            float n1v = 2.0f * mu12 + C1;                                 \
            float n2v = 2.0f * (Sp - mu12) + C2;                          \
            float sx2 = Sx * Sx, sy2 = Sy * Sy;                           \
            float d1  = sx2 + sy2 + C1;                                   \
            float d2  = (Sq - sx2 - sy2) + C2;                            \
            float sv  = (n1v * n2v) * __builtin_amdgcn_rcpf(d1 * d2);     \
            if (c0 + j < OW) acc += sv;                                   \
        }                                                                 \
    }

// main-loop row: consume incoming slot (row o+7) + outgoing po (row o-1),
// re-issue slot <- row o+9 (consumed at iter o+2), po <- row o (iter o+1).
#define ROWM(o, X0, X1, Y0, Y1) {                                         \
        float cx[8], cy[8], ox[8], oy[8];                                 \
        UNPACK8(X0, X1, cx)                                               \
        UNPACK8(Y0, Y1, cy)                                               \
        UNPACK8(px0, px1, ox)                                             \
        UNPACK8(py0, py1, oy)                                             \
        if ((o) + 2 < R1) ISSUE(X0, X1, Y0, Y1, (o) + 9)                  \
        if ((o) + 1 < R1) ISSUE(px0, px1, py0, py1, (o))                  \
        _Pragma("unroll")                                                 \
        for (int j = 0; j < 8; ++j) {                                     \
            vsx[j] = (vsx[j] - ox[j]) + cx[j];                            \
            vsy[j] = (vsy[j] - oy[j]) + cy[j];                            \
            vsq[j] = vsq[j] + ((cx[j] * cx[j] + cy[j] * cy[j]) -          \
                               (ox[j] * ox[j] + oy[j] * oy[j]));          \
            vsp[j] = vsp[j] + (cx[j] * cy[j] - ox[j] * oy[j]);            \
        }                                                                 \
        HORIZ_SSIM()                                                      \
    }

    // prime pipeline: A = row R0, B = row R0+1
    ISSUE(ax0, ax1, ay0, ay1, R0)
    ISSUE(bx0, bx1, by0, by1, R0 + 1)

    // warmup rows R0..R0+6 (roles alternate A,B,A,B,A,B,A)
    WARM(0, ax0, ax1, ay0, ay1)
    WARM(1, bx0, bx1, by0, by1)
    WARM(2, ax0, ax1, ay0, ay1)
    WARM(3, bx0, bx1, by0, by1)
    WARM(4, ax0, ax1, ay0, ay1)
    WARM(5, bx0, bx1, by0, by1)   // issues B <- row R0+7
    WARM(6, ax0, ax1, ay0, ay1)   // issues A <- row R0+8
    // now: B = row R0+7 (ready), A = row R0+8 (in flight)

    // first output row o = R0: consume B (row R0+7), add-only; prime
    // B <- row R0+9 (for o=R0+2) and po <- row R0 (for o=R0+1).
    {
        float cx[8], cy[8];
        UNPACK8(bx0, bx1, cx)
        UNPACK8(by0, by1, cy)
        ISSUE(bx0, bx1, by0, by1, R0 + 9)   // R0+2 < R1 always (>=9 rows)
        ISSUE(px0, px1, py0, py1, R0)       // R0+1 < R1 always
#pragma unroll
        for (int j = 0; j < 8; ++j) {
            vsx[j] = vsx[j] + cx[j];
            vsy[j] = vsy[j] + cy[j];
            vsq[j] = vsq[j] + (cx[j] * cx[j] + cy[j] * cy[j]);
            vsp[j] = vsp[j] + cx[j] * cy[j];
        }
        HORIZ_SSIM()
    }

    // main loop: o = R0+1 .. R1-1, roles alternate A,B,A,B,...
    // normal strip: 15 trips = 7 pairs + tail(A); last strip: 8 trips = 4 pairs.
    {
        int o = R0 + 1;
        while (o + 1 < R1) {
            ROWM(o,     ax0, ax1, ay0, ay1)
            ROWM(o + 1, bx0, bx1, by0, by1)
            o += 2;
        }
        if (o < R1) {
            ROWM(o, ax0, ax1, ay0, ay1)
        }
    }

    // ---- reduction: single wave -> one double atomic ----
#pragma unroll
    for (int off = 32; off > 0; off >>= 1) acc += __shfl_down(acc, off);
    if (l == 0) atomicAdd(acc_out, (double)acc);
}

extern "C" void kernel_launch(void* const* d_in, const int* in_sizes, int n_in,
                              void* d_out, int out_size, void* d_ws, size_t ws_size,
                              hipStream_t stream) {
    const float* gt = (const float*)d_in[0];
    const float* ni = (const float*)d_in[1];
    double* acc = (double*)d_ws;   // 8 bytes scratch, re-poisoned every call

    hipMemsetAsync(acc, 0, sizeof(double), stream);
    ssim_main<<<dim3(NWG), 64, 0, stream>>>(gt, ni, acc);
    finalize<<<1, 1, 0, stream>>>(acc, (float*)d_out);
}